// Round 8
// baseline (16013.264 us; speedup 1.0000x reference)
//
#include <hip/hip_runtime.h>
#include <math.h>

// Problem constants
#define BDIM 4096
#define TLEN 48
#define FEAT 35
#define HID 1024
#define H4 4096
#define KTOT 1152      // 1024 (hh) + 128 (ih, 70 real + 58 zero pad)

#define BH ((size_t)BDIM * HID)

typedef unsigned short u16;
typedef unsigned char u8;
typedef __bf16 bf16x8 __attribute__((ext_vector_type(8)));
typedef float f32x4 __attribute__((ext_vector_type(4)));
typedef u16 u16x8 __attribute__((ext_vector_type(8)));
typedef int v8i __attribute__((ext_vector_type(8)));
typedef int v4i __attribute__((ext_vector_type(4)));

#define SCALE1 0x7F7F7F7F   // E8M0 scale = 1.0 in every byte

__device__ __forceinline__ float b2f(u16 u) {
    union { float f; unsigned i; } v; v.i = ((unsigned)u) << 16; return v.f;
}
__device__ __forceinline__ u16 f2b(float f) {
    union { float f; unsigned i; } v; v.f = f;
    unsigned r = v.i + 0x7FFF + ((v.i >> 16) & 1);
    return (u16)(r >> 16);
}
__device__ __forceinline__ unsigned pk4_fp8(float a, float b, float c, float d) {
    int lo = __builtin_amdgcn_cvt_pk_fp8_f32(a, b, 0, false);
    int hi = __builtin_amdgcn_cvt_pk_fp8_f32(c, d, lo, true);
    return (unsigned)hi;
}
__device__ __forceinline__ u8 f2e4m3(float f) {
    return (u8)(__builtin_amdgcn_cvt_pk_fp8_f32(f, 0.f, 0, false) & 0xFF);
}
__device__ __forceinline__ float sigf(float x) { return __builtin_amdgcn_rcpf(1.f + __expf(-x)); }
__device__ __forceinline__ float tanh_fast(float x) { return 1.f - 2.f * __builtin_amdgcn_rcpf(1.f + __expf(2.f * x)); }

// ---------------- prep kernels ----------------
// Combined fp8 weight matrix W[4096][1152]. R7 reorder (64-wide gate groups so a
// 64-col N-tile holds all 4 gates of 16 j's):
// orig n = g*HID + j  ->  new n = (j>>4)*64 + g*16 + (j&15)
__global__ __launch_bounds__(256) void prep_w(const float* __restrict__ W_hh, const float* __restrict__ W_ih,
                                              u8* __restrict__ W) {
    int newn = blockIdx.x;
    int nbk = newn >> 6, rem = newn & 63, g = rem >> 4, jl = rem & 15;
    int orig = g * HID + nbk * 16 + jl;
    u8* dst = W + (size_t)newn * KTOT;
    const float* src = W_hh + (size_t)orig * HID;
    const float* src2 = W_ih + (size_t)orig * (2 * FEAT);
    for (int k4 = threadIdx.x; k4 < KTOT / 4; k4 += 256) {
        int k = k4 * 4;
        float f0, f1, f2, f3;
        if (k < HID) {
            f0 = src[k]; f1 = src[k + 1]; f2 = src[k + 2]; f3 = src[k + 3];
        } else {
            int q = k - HID;
            f0 = (q     < 2 * FEAT) ? src2[q]     : 0.f;
            f1 = (q + 1 < 2 * FEAT) ? src2[q + 1] : 0.f;
            f2 = (q + 2 < 2 * FEAT) ? src2[q + 2] : 0.f;
            f3 = (q + 3 < 2 * FEAT) ? src2[q + 3] : 0.f;
        }
        *(unsigned*)(dst + k) = pk4_fp8(f0, f1, f2, f3);
    }
}

__global__ __launch_bounds__(256) void prep_bias(const float* __restrict__ b_ih, const float* __restrict__ b_hh,
                                                 float* __restrict__ bias_r) {
    int newn = blockIdx.x * 256 + threadIdx.x;
    int nbk = newn >> 6, rem = newn & 63, g = rem >> 4, jl = rem & 15;
    int orig = g * HID + nbk * 16 + jl;
    bias_r[newn] = b_ih[orig] + b_hh[orig];
}

// tdWtb[j][f] bf16, [1024][64], f>=35 zero.
__global__ __launch_bounds__(256) void prep_tdwtb(const float* __restrict__ td_W, u16* __restrict__ tdWtb) {
    int idx = blockIdx.x * 256 + threadIdx.x;
    int row = idx >> 6, f = idx & 63;
    tdWtb[idx] = (f < FEAT) ? f2b(td_W[(size_t)row * FEAT + f]) : (u16)0;
}

// regW8[f][k] fp8, [48][1024], f>=35 zero.
__global__ __launch_bounds__(256) void prep_regw8(const float* __restrict__ reg_W, u8* __restrict__ regW8) {
    int row = blockIdx.x;           // 48
    int k = threadIdx.x * 4;        // 1024
    float f0 = 0.f, f1 = 0.f, f2 = 0.f, f3 = 0.f;
    if (row < FEAT) {
        const float* s = reg_W + (size_t)row * HID + k;
        f0 = s[0]; f1 = s[1]; f2 = s[2]; f3 = s[3];
    }
    *(unsigned*)(regW8 + (size_t)row * 1024 + k) = pk4_fp8(f0, f1, f2, f3);
}

// dbuf[t][b][64] bf16 (f>=35 zero), linear layout. Row = 128B.
__global__ __launch_bounds__(256) void prep_dbuf(const float* __restrict__ deltas, u16* __restrict__ dbuf) {
    int bid = blockIdx.x;                 // 48 * 128
    int t = bid >> 7, rc = bid & 127;
    int row = rc * 32 + (threadIdx.x >> 3), cch = threadIdx.x & 7;
    const float* dr = deltas + ((size_t)row * TLEN + t) * FEAT;
    u16x8 tv;
    #pragma unroll
    for (int k = 0; k < 8; ++k) {
        int f = cch * 8 + k;
        tv[k] = (f < FEAT) ? f2b(dr[f]) : (u16)0;
    }
    *(u16x8*)(dbuf + ((size_t)t * BDIM + row) * 64 + cch * 8) = tv;
}

// ---------------- stepR: regression + x_c + loss ----------------
// XCD-aware remap updated for R7 writer layout: X row panel mb (128 rows) is written
// by stepB blocks on XCD pair {(mb>>3)*2, +1}; land this block's rows there.
__global__ __launch_bounds__(256) void stepR(const float* __restrict__ values, const float* __restrict__ masks,
                                             const u8* __restrict__ regW8, const float* __restrict__ reg_b,
                                             u8* __restrict__ X, float* __restrict__ imput,
                                             float* __restrict__ xnum_part, float* __restrict__ xden_part,
                                             int t) {
    __shared__ float x_sh[16 * 35], m_sh[16 * 35];
    __shared__ float xhp[4][16][49];       // per-wave regression partials (padded)
    __shared__ float redbuf[8];

    int tid = threadIdx.x;
    int wave = tid >> 6, lane = tid & 63;
    int cl = lane & 15, quad = lane >> 4;
    int bid = blockIdx.x;
    int xs = bid & 7, qs = bid >> 3;       // bijective XCD-aware remap
    int b0 = ((xs >> 1) * 8 + (qs & 7)) * 128 + ((xs & 1) * 4 + (qs >> 3)) * 16;

    for (int i = tid; i < 16 * 35; i += 256) {
        int b = i / 35, f = i - b * 35;
        size_t g = ((size_t)(b0 + b) * TLEN + t) * FEAT + f;
        x_sh[i] = values[g];
        m_sh[i] = masks[g];
    }
    __syncthreads();

    // ---- regression via MX-fp8 MFMA (K split: wave covers K [wave*256, +256)) ----
    f32x4 racc[3];
    #pragma unroll
    for (int nt = 0; nt < 3; ++nt) racc[nt] = (f32x4){0.f, 0.f, 0.f, 0.f};
    const u8* xrow = X + (size_t)(b0 + cl) * KTOT + wave * 256;
    #pragma unroll
    for (int it = 0; it < 2; ++it) {
        v8i av = *(const v8i*)(xrow + it * 128 + quad * 32);
        #pragma unroll
        for (int nt = 0; nt < 3; ++nt) {
            v8i bvv = *(const v8i*)(regW8 + (size_t)(nt * 16 + cl) * 1024 + wave * 256 + it * 128 + quad * 32);
            racc[nt] = __builtin_amdgcn_mfma_scale_f32_16x16x128_f8f6f4(
                av, bvv, racc[nt], 0, 0, 0, SCALE1, 0, SCALE1);
        }
    }
    #pragma unroll
    for (int nt = 0; nt < 3; ++nt)
        #pragma unroll
        for (int r = 0; r < 4; ++r)
            xhp[wave][quad * 4 + r][nt * 16 + cl] = racc[nt][r];
    __syncthreads();

    // ---- epilogue: x_c, imputations, X tail (fp8), loss partials ----
    float lossN = 0.f, lossD = 0.f;
    for (int i = tid; i < 16 * 35; i += 256) {
        int b = i / 35, f = i - b * 35;
        float xh = xhp[0][b][f] + xhp[1][b][f] + xhp[2][b][f] + xhp[3][b][f] + reg_b[f];
        float xv = x_sh[i], mv = m_sh[i];
        float xc = mv * xv + (1.f - mv) * xh;
        imput[((size_t)(b0 + b) * TLEN + t) * FEAT + f] = xc;
        u8* Xr = X + (size_t)(b0 + b) * KTOT;
        Xr[HID + f] = f2e4m3(xc);
        Xr[HID + FEAT + f] = f2e4m3(mv);
        lossN += fabsf(xv - xh) * mv;
        lossD += mv;
    }
    #pragma unroll
    for (int off = 32; off; off >>= 1) {
        lossN += __shfl_down(lossN, off);
        lossD += __shfl_down(lossD, off);
    }
    if (lane == 0) { redbuf[wave] = lossN; redbuf[4 + wave] = lossD; }
    __syncthreads();
    if (tid == 0) {
        xnum_part[t * 256 + blockIdx.x] = redbuf[0] + redbuf[1] + redbuf[2] + redbuf[3];
        xden_part[t * 256 + blockIdx.x] = redbuf[4] + redbuf[5] + redbuf[6] + redbuf[7];
    }
}

// ---------------- stepB: MX-fp8 MFMA gates GEMM + fused LSTM cell + inline gamma(t+1) ----------------
// R7: SAME loop-body shape as the proven baseline (barrier -> global_load_lds ->
// barrier -> ds_read -> MFMA, single buffer), but tile shrunk 256x128 -> 128x64
// (acc[2][4]=32 f32/thread) + __launch_bounds__(256,4) so 4 blocks/CU are resident
// (was 2) -- attacks the ~80% drain-stall idle time with cross-block overlap.
// Grid 2048 = 32mb x 64nb, bijective XCD map: 8mb x 32nb per XCD (1.2MB X + 2.4MB W in L2).
// W8/bias use the 64-wide gate reorder so each block owns all 4 gates of its 16 j's.
// td_b quirk formula (jtile + quad*4 + r) preserved bit-identically from the passing kernel.
__global__ __launch_bounds__(256, 4) void stepB(const u8* __restrict__ X, const u8* __restrict__ W,
                                                const float* __restrict__ bias_r, const u16* __restrict__ tdWtb,
                                                const float* __restrict__ td_b, const u16* __restrict__ dbufT1,
                                                u16* __restrict__ c, u8* __restrict__ Xn,
                                                u16* __restrict__ h, int last) {
    __shared__ u8 As[128 * 128];   // 16 KB
    __shared__ u8 Bs[64 * 128];    // 8 KB
    int bid = blockIdx.x;
    int xcd = bid & 7, r0 = bid >> 3;            // r0 in [0,256)
    int mb = (xcd >> 1) * 8 + (r0 & 7);          // [0,32)
    int nb = (xcd & 1) * 32 + (r0 >> 3);         // [0,64)
    int tid = threadIdx.x;
    int wave = tid >> 6, lane = tid & 63;
    int lrow = lane >> 3;            // 0..7 row within 8-row staging group
    int gchunk = (lane & 7) ^ lrow;  // swizzled global 16B-chunk to fetch
    int cl = lane & 15, quad = lane >> 4;
    int c7 = cl & 7;

    f32x4 acc[2][4];
    #pragma unroll
    for (int mi = 0; mi < 2; ++mi)
        #pragma unroll
        for (int ni = 0; ni < 4; ++ni) acc[mi][ni] = (f32x4){0.f, 0.f, 0.f, 0.f};

    for (int kt = 0; kt < KTOT / 128; ++kt) {     // 9 iterations
        __syncthreads();
        #pragma unroll
        for (int it = 0; it < 4; ++it) {
            int rl = wave * 32 + it * 8;          // A rows [wave*32 .. +32)
            const u8* ga = X + (size_t)(mb * 128 + rl + lrow) * KTOT + kt * 128 + gchunk * 16;
            __builtin_amdgcn_global_load_lds((const __attribute__((address_space(1))) void*)ga,
                                             (__attribute__((address_space(3))) void*)(As + rl * 128),
                                             16, 0, 0);
        }
        #pragma unroll
        for (int it = 0; it < 2; ++it) {
            int rl = wave * 16 + it * 8;          // B rows [wave*16 .. +16)
            const u8* gb = W + (size_t)(nb * 64 + rl + lrow) * KTOT + kt * 128 + gchunk * 16;
            __builtin_amdgcn_global_load_lds((const __attribute__((address_space(1))) void*)gb,
                                             (__attribute__((address_space(3))) void*)(Bs + rl * 128),
                                             16, 0, 0);
        }
        __syncthreads();

        v8i av[2];
        #pragma unroll
        for (int mi = 0; mi < 2; ++mi) {
            const u8* base = As + (wave * 32 + mi * 16 + cl) * 128;
            v4i lo = *(const v4i*)(base + (((2 * quad) ^ c7) << 4));
            v4i hi = *(const v4i*)(base + (((2 * quad + 1) ^ c7) << 4));
            av[mi] = (v8i){lo[0], lo[1], lo[2], lo[3], hi[0], hi[1], hi[2], hi[3]};
        }
        #pragma unroll
        for (int ni = 0; ni < 4; ++ni) {
            const u8* base = Bs + (ni * 16 + cl) * 128;
            v4i lo = *(const v4i*)(base + (((2 * quad) ^ c7) << 4));
            v4i hi = *(const v4i*)(base + (((2 * quad + 1) ^ c7) << 4));
            v8i bvv = (v8i){lo[0], lo[1], lo[2], lo[3], hi[0], hi[1], hi[2], hi[3]};
            #pragma unroll
            for (int mi = 0; mi < 2; ++mi)
                acc[mi][ni] = __builtin_amdgcn_mfma_scale_f32_16x16x128_f8f6f4(
                    av[mi], bvv, acc[mi][ni], 0, 0, 0, SCALE1, 0, SCALE1);
        }
    }

    // ---- restage As with deltas(t+1) bf16 [128 rows][64] for inline gamma ----
    if (!last) {
        __syncthreads();   // all waves done with K-loop LDS
        const u8* gd = (const u8*)dbufT1 + (size_t)(mb * 128) * 128;
        #pragma unroll
        for (int it = 0; it < 4; ++it) {
            int rl = wave * 32 + it * 8;
            __builtin_amdgcn_global_load_lds((const __attribute__((address_space(1))) void*)(gd + (size_t)(rl + lrow) * 128 + gchunk * 16),
                                             (__attribute__((address_space(3))) void*)(As + rl * 128),
                                             16, 0, 0);
        }
        __syncthreads();
    }

    // ---- fused epilogue: gamma(t+1) MFMA per mi-tile + LSTM cell ----
    const u16* Asw = (const u16*)As;
    int swc0 = quad ^ c7, swc1 = (4 + quad) ^ c7;
    #pragma unroll
    for (int mi = 0; mi < 2; ++mi) {
        float gam[4] = {1.f, 1.f, 1.f, 1.f};
        if (!last) {
            int arow = wave * 32 + mi * 16 + cl;
            bf16x8 a0 = *(const bf16x8*)(Asw + arow * 64 + swc0 * 8);
            bf16x8 a1 = *(const bf16x8*)(Asw + arow * 64 + swc1 * 8);
            const u16* tw = tdWtb + (size_t)(nb * 16 + cl) * 64;
            bf16x8 b0v = *(const bf16x8*)(tw + quad * 8);
            bf16x8 b1v = *(const bf16x8*)(tw + 32 + quad * 8);
            f32x4 g4 = (f32x4){0.f, 0.f, 0.f, 0.f};
            g4 = __builtin_amdgcn_mfma_f32_16x16x32_bf16(a0, b0v, g4, 0, 0, 0);
            g4 = __builtin_amdgcn_mfma_f32_16x16x32_bf16(a1, b1v, g4, 0, 0, 0);
            float4 tb = *(const float4*)(td_b + nb * 16 + quad * 4);
            float tbv[4] = {tb.x, tb.y, tb.z, tb.w};
            #pragma unroll
            for (int r = 0; r < 4; ++r)
                gam[r] = __expf(-fmaxf(g4[r] + tbv[r], 0.f));
        }
        #pragma unroll
        for (int r = 0; r < 4; ++r) {
            int b = mb * 128 + wave * 32 + mi * 16 + quad * 4 + r;
            int j = nb * 16 + cl;
            float iv = acc[mi][0][r] + bias_r[nb * 64 + cl];
            float fv = acc[mi][1][r] + bias_r[nb * 64 + 16 + cl];
            float gg = acc[mi][2][r] + bias_r[nb * 64 + 32 + cl];
            float ov = acc[mi][3][r] + bias_r[nb * 64 + 48 + cl];
            iv = sigf(iv); fv = sigf(fv); ov = sigf(ov); gg = tanh_fast(gg);
            size_t idx = (size_t)b * HID + j;
            float cn = fv * b2f(c[idx]) + iv * gg;
            c[idx] = f2b(cn);
            float hn = ov * tanh_fast(cn);
            if (last) {
                h[idx] = f2b(hn);
            } else {
                Xn[(size_t)b * KTOT + j] = f2e4m3(hn * gam[r]);
            }
        }
    }
}

// ---------------- final kernels (atomic-free) ----------------
__global__ __launch_bounds__(256) void finalY(const u16* __restrict__ h, const float* __restrict__ out_W,
                                              const float* __restrict__ out_b, const float* __restrict__ labels,
                                              const float* __restrict__ is_train, float* __restrict__ preds,
                                              float* __restrict__ bce_part, float* __restrict__ it_part) {
    __shared__ float wbuf[8];
    int tid = threadIdx.x;
    int wave = tid >> 6, lane = tid & 63;
    int cl = lane & 15, quad = lane >> 4;
    int b = blockIdx.x * 16 + wave * 4 + quad;
    const u16x8* hp = (const u16x8*)(h + (size_t)b * HID + cl * 64);
    const float4* wp = (const float4*)(out_W + cl * 64);
    float s = 0.f;
    #pragma unroll
    for (int i = 0; i < 8; ++i) {
        u16x8 hv = hp[i];
        float4 wa = wp[2 * i], wb = wp[2 * i + 1];
        s += b2f(hv[0]) * wa.x + b2f(hv[1]) * wa.y + b2f(hv[2]) * wa.z + b2f(hv[3]) * wa.w
           + b2f(hv[4]) * wb.x + b2f(hv[5]) * wb.y + b2f(hv[6]) * wb.z + b2f(hv[7]) * wb.w;
    }
    s += __shfl_down(s, 8, 16);
    s += __shfl_down(s, 4, 16);
    s += __shfl_down(s, 2, 16);
    s += __shfl_down(s, 1, 16);
    float v1 = 0.f, v2 = 0.f;
    if (cl == 0) {
        float y = s + out_b[0];
        preds[b] = 1.f / (1.f + expf(-y));
        float lab = labels[b], it = is_train[b];
        float mv = fmaxf(-y, 0.f);
        float bce = y - y * lab + mv + logf(expf(-mv) + expf(-y - mv));
        v1 = bce * it; v2 = it;
    }
    v1 += __shfl_xor(v1, 16); v2 += __shfl_xor(v2, 16);
    v1 += __shfl_xor(v1, 32); v2 += __shfl_xor(v2, 32);
    if (lane == 0) { wbuf[wave] = v1; wbuf[4 + wave] = v2; }
    __syncthreads();
    if (tid == 0) {
        bce_part[blockIdx.x] = wbuf[0] + wbuf[1] + wbuf[2] + wbuf[3];
        it_part[blockIdx.x]  = wbuf[4] + wbuf[5] + wbuf[6] + wbuf[7];
    }
}

__global__ __launch_bounds__(256) void finalZ(const float* __restrict__ xnum, const float* __restrict__ xden,
                                              const float* __restrict__ bce_part, const float* __restrict__ it_part,
                                              float* __restrict__ out0) {
    __shared__ float wbuf[12];
    int tid = threadIdx.x, wave = tid >> 6, lane = tid & 63;
    float bs = bce_part[tid], is = it_part[tid];
    #pragma unroll
    for (int off = 32; off; off >>= 1) { bs += __shfl_down(bs, off); is += __shfl_down(is, off); }
    float xl = 0.f;
    for (int t = wave; t < TLEN; t += 4) {
        float n = 0.f, d = 0.f;
        #pragma unroll
        for (int i = 0; i < 4; ++i) { n += xnum[t * 256 + lane + i * 64]; d += xden[t * 256 + lane + i * 64]; }
        #pragma unroll
        for (int off = 32; off; off >>= 1) { n += __shfl_down(n, off); d += __shfl_down(d, off); }
        if (lane == 0) xl += n / (d + 1e-5f);
    }
    if (lane == 0) { wbuf[wave] = xl; wbuf[4 + wave] = bs; wbuf[8 + wave] = is; }
    __syncthreads();
    if (tid == 0) {
        float XL = wbuf[0] + wbuf[1] + wbuf[2] + wbuf[3];
        float BS = wbuf[4] + wbuf[5] + wbuf[6] + wbuf[7];
        float IS = wbuf[8] + wbuf[9] + wbuf[10] + wbuf[11];
        out0[0] = 0.3f * XL + BS / (IS + 1e-5f);
    }
}

// ---------------- launch ----------------
extern "C" void kernel_launch(void* const* d_in, const int* in_sizes, int n_in,
                              void* d_out, int out_size, void* d_ws, size_t ws_size,
                              hipStream_t stream) {
    const float* values   = (const float*)d_in[0];
    const float* masks    = (const float*)d_in[1];
    const float* deltas   = (const float*)d_in[2];
    const float* labels   = (const float*)d_in[3];
    const float* is_train = (const float*)d_in[4];
    const float* td_W     = (const float*)d_in[5];
    const float* td_b     = (const float*)d_in[6];
    const float* W_ih     = (const float*)d_in[7];
    const float* W_hh     = (const float*)d_in[8];
    const float* b_ih     = (const float*)d_in[9];
    const float* b_hh     = (const float*)d_in[10];
    const float* reg_W    = (const float*)d_in[11];
    const float* reg_b    = (const float*)d_in[12];
    const float* out_W    = (const float*)d_in[13];
    const float* out_b    = (const float*)d_in[14];

    float* out = (float*)d_out;

    // workspace: c bf16[BH] | h bf16[BH] | dbuf bf16[48*4096*64] | Xa u8[B*KTOT] | Xb u8[B*KTOT]
    //            | W8 u8[H4*KTOT] | bias f32[H4] | tdWtb bf16[64K] | regW8 u8[48*1024] | parts
    u16*   c      = (u16*)d_ws;
    u16*   h      = c + BH;
    u16*   dbuf   = h + BH;
    u8*    Xa     = (u8*)(dbuf + (size_t)TLEN * BDIM * 64);
    u8*    Xb     = Xa + (size_t)BDIM * KTOT;
    u8*    W8     = Xb + (size_t)BDIM * KTOT;
    float* bias_r = (float*)(W8 + (size_t)H4 * KTOT);
    u16*   tdWtb  = (u16*)(bias_r + H4);
    u8*    regW8  = (u8*)(tdWtb + 1024 * 64);
    float* xnum_part = (float*)(regW8 + 48 * 1024);
    float* xden_part = xnum_part + TLEN * 256;
    float* bce_part  = xden_part + TLEN * 256;
    float* it_part   = bce_part + 256;

    hipMemsetAsync(c, 0, BH * sizeof(u16), stream);                 // c = 0
    hipMemsetAsync(Xa, 0, (size_t)BDIM * KTOT, stream);             // X_hdec(0) = 0 + pad zeros
    hipMemsetAsync(Xb, 0, (size_t)BDIM * KTOT, stream);             // pad zeros (stay zero forever)

    prep_w<<<H4, 256, 0, stream>>>(W_hh, W_ih, W8);
    prep_bias<<<H4 / 256, 256, 0, stream>>>(b_ih, b_hh, bias_r);
    prep_tdwtb<<<256, 256, 0, stream>>>(td_W, tdWtb);
    prep_regw8<<<48, 256, 0, stream>>>(reg_W, regW8);
    prep_dbuf<<<TLEN * 128, 256, 0, stream>>>(deltas, dbuf);

    float* imput = out + 1 + BDIM;
    for (int t = 0; t < TLEN; t++) {
        u8* cur = (t & 1) ? Xb : Xa;
        u8* nxt = (t & 1) ? Xa : Xb;
        const u16* dT1 = dbuf + (size_t)((t + 1 < TLEN) ? (t + 1) : 0) * BDIM * 64;
        stepR<<<BDIM / 16, 256, 0, stream>>>(values, masks, regW8, reg_b, cur, imput,
                                             xnum_part, xden_part, t);
        stepB<<<2048, 256, 0, stream>>>(cur, W8, bias_r, tdWtb, td_b, dT1, c, nxt, h, t == TLEN - 1);
    }
    finalY<<<BDIM / 16, 256, 0, stream>>>(h, out_W, out_b, labels, is_train, out + 1, bce_part, it_part);
    finalZ<<<1, 256, 0, stream>>>(xnum_part, xden_part, bce_part, it_part, out);
}

// Round 9
// 6680.618 us; speedup vs baseline: 2.3970x; 2.3970x over previous
//
#include <hip/hip_runtime.h>
#include <math.h>

// Problem constants
#define BDIM 4096
#define TLEN 48
#define FEAT 35
#define HID 1024
#define H4 4096
#define KTOT 1152      // 1024 (hh) + 128 (ih, 70 real + 58 zero pad)

#define BH ((size_t)BDIM * HID)

typedef unsigned short u16;
typedef unsigned char u8;
typedef __bf16 bf16x8 __attribute__((ext_vector_type(8)));
typedef float f32x4 __attribute__((ext_vector_type(4)));
typedef u16 u16x8 __attribute__((ext_vector_type(8)));
typedef int v8i __attribute__((ext_vector_type(8)));
typedef int v4i __attribute__((ext_vector_type(4)));

#define SCALE1 0x7F7F7F7F   // E8M0 scale = 1.0 in every byte

__device__ __forceinline__ float b2f(u16 u) {
    union { float f; unsigned i; } v; v.i = ((unsigned)u) << 16; return v.f;
}
__device__ __forceinline__ u16 f2b(float f) {
    union { float f; unsigned i; } v; v.f = f;
    unsigned r = v.i + 0x7FFF + ((v.i >> 16) & 1);
    return (u16)(r >> 16);
}
__device__ __forceinline__ unsigned pk4_fp8(float a, float b, float c, float d) {
    int lo = __builtin_amdgcn_cvt_pk_fp8_f32(a, b, 0, false);
    int hi = __builtin_amdgcn_cvt_pk_fp8_f32(c, d, lo, true);
    return (unsigned)hi;
}
__device__ __forceinline__ u8 f2e4m3(float f) {
    return (u8)(__builtin_amdgcn_cvt_pk_fp8_f32(f, 0.f, 0, false) & 0xFF);
}
__device__ __forceinline__ float sigf(float x) { return __builtin_amdgcn_rcpf(1.f + __expf(-x)); }
__device__ __forceinline__ float tanh_fast(float x) { return 1.f - 2.f * __builtin_amdgcn_rcpf(1.f + __expf(2.f * x)); }

// ---------------- prep kernels ----------------
// Combined fp8 weight matrix W[4096][1152]. 64-wide gate groups so a 64-col N-tile
// holds all 4 gates of 16 j's:  orig n = g*HID + j  ->  new n = (j>>4)*64 + g*16 + (j&15)
__global__ __launch_bounds__(256) void prep_w(const float* __restrict__ W_hh, const float* __restrict__ W_ih,
                                              u8* __restrict__ W) {
    int newn = blockIdx.x;
    int nbk = newn >> 6, rem = newn & 63, g = rem >> 4, jl = rem & 15;
    int orig = g * HID + nbk * 16 + jl;
    u8* dst = W + (size_t)newn * KTOT;
    const float* src = W_hh + (size_t)orig * HID;
    const float* src2 = W_ih + (size_t)orig * (2 * FEAT);
    for (int k4 = threadIdx.x; k4 < KTOT / 4; k4 += 256) {
        int k = k4 * 4;
        float f0, f1, f2, f3;
        if (k < HID) {
            f0 = src[k]; f1 = src[k + 1]; f2 = src[k + 2]; f3 = src[k + 3];
        } else {
            int q = k - HID;
            f0 = (q     < 2 * FEAT) ? src2[q]     : 0.f;
            f1 = (q + 1 < 2 * FEAT) ? src2[q + 1] : 0.f;
            f2 = (q + 2 < 2 * FEAT) ? src2[q + 2] : 0.f;
            f3 = (q + 3 < 2 * FEAT) ? src2[q + 3] : 0.f;
        }
        *(unsigned*)(dst + k) = pk4_fp8(f0, f1, f2, f3);
    }
}

__global__ __launch_bounds__(256) void prep_bias(const float* __restrict__ b_ih, const float* __restrict__ b_hh,
                                                 float* __restrict__ bias_r) {
    int newn = blockIdx.x * 256 + threadIdx.x;
    int nbk = newn >> 6, rem = newn & 63, g = rem >> 4, jl = rem & 15;
    int orig = g * HID + nbk * 16 + jl;
    bias_r[newn] = b_ih[orig] + b_hh[orig];
}

// tdWtb[j][f] bf16, [1024][64], f>=35 zero.
__global__ __launch_bounds__(256) void prep_tdwtb(const float* __restrict__ td_W, u16* __restrict__ tdWtb) {
    int idx = blockIdx.x * 256 + threadIdx.x;
    int row = idx >> 6, f = idx & 63;
    tdWtb[idx] = (f < FEAT) ? f2b(td_W[(size_t)row * FEAT + f]) : (u16)0;
}

// regW8[f][k] fp8, [48][1024], f>=35 zero.
__global__ __launch_bounds__(256) void prep_regw8(const float* __restrict__ reg_W, u8* __restrict__ regW8) {
    int row = blockIdx.x;           // 48
    int k = threadIdx.x * 4;        // 1024
    float f0 = 0.f, f1 = 0.f, f2 = 0.f, f3 = 0.f;
    if (row < FEAT) {
        const float* s = reg_W + (size_t)row * HID + k;
        f0 = s[0]; f1 = s[1]; f2 = s[2]; f3 = s[3];
    }
    *(unsigned*)(regW8 + (size_t)row * 1024 + k) = pk4_fp8(f0, f1, f2, f3);
}

// dbuf[t][b][64] bf16 (f>=35 zero), linear layout. Row = 128B.
__global__ __launch_bounds__(256) void prep_dbuf(const float* __restrict__ deltas, u16* __restrict__ dbuf) {
    int bid = blockIdx.x;                 // 48 * 128
    int t = bid >> 7, rc = bid & 127;
    int row = rc * 32 + (threadIdx.x >> 3), cch = threadIdx.x & 7;
    const float* dr = deltas + ((size_t)row * TLEN + t) * FEAT;
    u16x8 tv;
    #pragma unroll
    for (int k = 0; k < 8; ++k) {
        int f = cch * 8 + k;
        tv[k] = (f < FEAT) ? f2b(dr[f]) : (u16)0;
    }
    *(u16x8*)(dbuf + ((size_t)t * BDIM + row) * 64 + cch * 8) = tv;
}

// ---------------- stepR: regression + x_c + loss ----------------
__global__ __launch_bounds__(256) void stepR(const float* __restrict__ values, const float* __restrict__ masks,
                                             const u8* __restrict__ regW8, const float* __restrict__ reg_b,
                                             u8* __restrict__ X, float* __restrict__ imput,
                                             float* __restrict__ xnum_part, float* __restrict__ xden_part,
                                             int t) {
    __shared__ float x_sh[16 * 35], m_sh[16 * 35];
    __shared__ float xhp[4][16][49];       // per-wave regression partials (padded)
    __shared__ float redbuf[8];

    int tid = threadIdx.x;
    int wave = tid >> 6, lane = tid & 63;
    int cl = lane & 15, quad = lane >> 4;
    int bid = blockIdx.x;
    int xs = bid & 7, qs = bid >> 3;       // bijective XCD-aware remap
    int b0 = ((xs >> 1) * 8 + (qs & 7)) * 128 + ((xs & 1) * 4 + (qs >> 3)) * 16;

    for (int i = tid; i < 16 * 35; i += 256) {
        int b = i / 35, f = i - b * 35;
        size_t g = ((size_t)(b0 + b) * TLEN + t) * FEAT + f;
        x_sh[i] = values[g];
        m_sh[i] = masks[g];
    }
    __syncthreads();

    // ---- regression via MX-fp8 MFMA (K split: wave covers K [wave*256, +256)) ----
    f32x4 racc[3];
    #pragma unroll
    for (int nt = 0; nt < 3; ++nt) racc[nt] = (f32x4){0.f, 0.f, 0.f, 0.f};
    const u8* xrow = X + (size_t)(b0 + cl) * KTOT + wave * 256;
    #pragma unroll
    for (int it = 0; it < 2; ++it) {
        v8i av = *(const v8i*)(xrow + it * 128 + quad * 32);
        #pragma unroll
        for (int nt = 0; nt < 3; ++nt) {
            v8i bvv = *(const v8i*)(regW8 + (size_t)(nt * 16 + cl) * 1024 + wave * 256 + it * 128 + quad * 32);
            racc[nt] = __builtin_amdgcn_mfma_scale_f32_16x16x128_f8f6f4(
                av, bvv, racc[nt], 0, 0, 0, SCALE1, 0, SCALE1);
        }
    }
    #pragma unroll
    for (int nt = 0; nt < 3; ++nt)
        #pragma unroll
        for (int r = 0; r < 4; ++r)
            xhp[wave][quad * 4 + r][nt * 16 + cl] = racc[nt][r];
    __syncthreads();

    // ---- epilogue: x_c, imputations, X tail (fp8), loss partials ----
    float lossN = 0.f, lossD = 0.f;
    for (int i = tid; i < 16 * 35; i += 256) {
        int b = i / 35, f = i - b * 35;
        float xh = xhp[0][b][f] + xhp[1][b][f] + xhp[2][b][f] + xhp[3][b][f] + reg_b[f];
        float xv = x_sh[i], mv = m_sh[i];
        float xc = mv * xv + (1.f - mv) * xh;
        imput[((size_t)(b0 + b) * TLEN + t) * FEAT + f] = xc;
        u8* Xr = X + (size_t)(b0 + b) * KTOT;
        Xr[HID + f] = f2e4m3(xc);
        Xr[HID + FEAT + f] = f2e4m3(mv);
        lossN += fabsf(xv - xh) * mv;
        lossD += mv;
    }
    #pragma unroll
    for (int off = 32; off; off >>= 1) {
        lossN += __shfl_down(lossN, off);
        lossD += __shfl_down(lossD, off);
    }
    if (lane == 0) { redbuf[wave] = lossN; redbuf[4 + wave] = lossD; }
    __syncthreads();
    if (tid == 0) {
        xnum_part[t * 256 + blockIdx.x] = redbuf[0] + redbuf[1] + redbuf[2] + redbuf[3];
        xden_part[t * 256 + blockIdx.x] = redbuf[4] + redbuf[5] + redbuf[6] + redbuf[7];
    }
}

// ---------------- stepB: MX-fp8 MFMA gates GEMM + fused LSTM cell + inline gamma(t+1) ----------------
// R8: identical to R7 (128x64 tile, acc[2][4]=32 f32, grid 2048, verified indexing)
// EXCEPT __launch_bounds__(256,4) -> (256,2). R7 lesson: any waves_per_eu cap other
// than 2 makes the backend abandon AGPR placement and spill (VGPR=64, 1.1GB scratch).
// With the proven (256,2) budget there is zero spill pressure; if actual usage lands
// <=128 unified regs/wave the HW gives 4 waves/SIMD (4 blocks/CU) automatically.
__global__ __launch_bounds__(256, 2) void stepB(const u8* __restrict__ X, const u8* __restrict__ W,
                                                const float* __restrict__ bias_r, const u16* __restrict__ tdWtb,
                                                const float* __restrict__ td_b, const u16* __restrict__ dbufT1,
                                                u16* __restrict__ c, u8* __restrict__ Xn,
                                                u16* __restrict__ h, int last) {
    __shared__ u8 As[128 * 128];   // 16 KB
    __shared__ u8 Bs[64 * 128];    // 8 KB
    int bid = blockIdx.x;
    int xcd = bid & 7, r0 = bid >> 3;            // r0 in [0,256)
    int mb = (xcd >> 1) * 8 + (r0 & 7);          // [0,32)
    int nb = (xcd & 1) * 32 + (r0 >> 3);         // [0,64)
    int tid = threadIdx.x;
    int wave = tid >> 6, lane = tid & 63;
    int lrow = lane >> 3;            // 0..7 row within 8-row staging group
    int gchunk = (lane & 7) ^ lrow;  // swizzled global 16B-chunk to fetch
    int cl = lane & 15, quad = lane >> 4;
    int c7 = cl & 7;

    f32x4 acc[2][4];
    #pragma unroll
    for (int mi = 0; mi < 2; ++mi)
        #pragma unroll
        for (int ni = 0; ni < 4; ++ni) acc[mi][ni] = (f32x4){0.f, 0.f, 0.f, 0.f};

    for (int kt = 0; kt < KTOT / 128; ++kt) {     // 9 iterations
        __syncthreads();
        #pragma unroll
        for (int it = 0; it < 4; ++it) {
            int rl = wave * 32 + it * 8;          // A rows [wave*32 .. +32)
            const u8* ga = X + (size_t)(mb * 128 + rl + lrow) * KTOT + kt * 128 + gchunk * 16;
            __builtin_amdgcn_global_load_lds((const __attribute__((address_space(1))) void*)ga,
                                             (__attribute__((address_space(3))) void*)(As + rl * 128),
                                             16, 0, 0);
        }
        #pragma unroll
        for (int it = 0; it < 2; ++it) {
            int rl = wave * 16 + it * 8;          // B rows [wave*16 .. +16)
            const u8* gb = W + (size_t)(nb * 64 + rl + lrow) * KTOT + kt * 128 + gchunk * 16;
            __builtin_amdgcn_global_load_lds((const __attribute__((address_space(1))) void*)gb,
                                             (__attribute__((address_space(3))) void*)(Bs + rl * 128),
                                             16, 0, 0);
        }
        __syncthreads();

        v8i av[2];
        #pragma unroll
        for (int mi = 0; mi < 2; ++mi) {
            const u8* base = As + (wave * 32 + mi * 16 + cl) * 128;
            v4i lo = *(const v4i*)(base + (((2 * quad) ^ c7) << 4));
            v4i hi = *(const v4i*)(base + (((2 * quad + 1) ^ c7) << 4));
            av[mi] = (v8i){lo[0], lo[1], lo[2], lo[3], hi[0], hi[1], hi[2], hi[3]};
        }
        #pragma unroll
        for (int ni = 0; ni < 4; ++ni) {
            const u8* base = Bs + (ni * 16 + cl) * 128;
            v4i lo = *(const v4i*)(base + (((2 * quad) ^ c7) << 4));
            v4i hi = *(const v4i*)(base + (((2 * quad + 1) ^ c7) << 4));
            v8i bvv = (v8i){lo[0], lo[1], lo[2], lo[3], hi[0], hi[1], hi[2], hi[3]};
            #pragma unroll
            for (int mi = 0; mi < 2; ++mi)
                acc[mi][ni] = __builtin_amdgcn_mfma_scale_f32_16x16x128_f8f6f4(
                    av[mi], bvv, acc[mi][ni], 0, 0, 0, SCALE1, 0, SCALE1);
        }
    }

    // ---- restage As with deltas(t+1) bf16 [128 rows][64] for inline gamma ----
    if (!last) {
        __syncthreads();   // all waves done with K-loop LDS
        const u8* gd = (const u8*)dbufT1 + (size_t)(mb * 128) * 128;
        #pragma unroll
        for (int it = 0; it < 4; ++it) {
            int rl = wave * 32 + it * 8;
            __builtin_amdgcn_global_load_lds((const __attribute__((address_space(1))) void*)(gd + (size_t)(rl + lrow) * 128 + gchunk * 16),
                                             (__attribute__((address_space(3))) void*)(As + rl * 128),
                                             16, 0, 0);
        }
        __syncthreads();
    }

    // ---- fused epilogue: gamma(t+1) MFMA per mi-tile + LSTM cell ----
    const u16* Asw = (const u16*)As;
    int swc0 = quad ^ c7, swc1 = (4 + quad) ^ c7;
    #pragma unroll
    for (int mi = 0; mi < 2; ++mi) {
        float gam[4] = {1.f, 1.f, 1.f, 1.f};
        if (!last) {
            int arow = wave * 32 + mi * 16 + cl;
            bf16x8 a0 = *(const bf16x8*)(Asw + arow * 64 + swc0 * 8);
            bf16x8 a1 = *(const bf16x8*)(Asw + arow * 64 + swc1 * 8);
            const u16* tw = tdWtb + (size_t)(nb * 16 + cl) * 64;
            bf16x8 b0v = *(const bf16x8*)(tw + quad * 8);
            bf16x8 b1v = *(const bf16x8*)(tw + 32 + quad * 8);
            f32x4 g4 = (f32x4){0.f, 0.f, 0.f, 0.f};
            g4 = __builtin_amdgcn_mfma_f32_16x16x32_bf16(a0, b0v, g4, 0, 0, 0);
            g4 = __builtin_amdgcn_mfma_f32_16x16x32_bf16(a1, b1v, g4, 0, 0, 0);
            float4 tb = *(const float4*)(td_b + nb * 16 + quad * 4);
            float tbv[4] = {tb.x, tb.y, tb.z, tb.w};
            #pragma unroll
            for (int r = 0; r < 4; ++r)
                gam[r] = __expf(-fmaxf(g4[r] + tbv[r], 0.f));
        }
        #pragma unroll
        for (int r = 0; r < 4; ++r) {
            int b = mb * 128 + wave * 32 + mi * 16 + quad * 4 + r;
            int j = nb * 16 + cl;
            float iv = acc[mi][0][r] + bias_r[nb * 64 + cl];
            float fv = acc[mi][1][r] + bias_r[nb * 64 + 16 + cl];
            float gg = acc[mi][2][r] + bias_r[nb * 64 + 32 + cl];
            float ov = acc[mi][3][r] + bias_r[nb * 64 + 48 + cl];
            iv = sigf(iv); fv = sigf(fv); ov = sigf(ov); gg = tanh_fast(gg);
            size_t idx = (size_t)b * HID + j;
            float cn = fv * b2f(c[idx]) + iv * gg;
            c[idx] = f2b(cn);
            float hn = ov * tanh_fast(cn);
            if (last) {
                h[idx] = f2b(hn);
            } else {
                Xn[(size_t)b * KTOT + j] = f2e4m3(hn * gam[r]);
            }
        }
    }
}

// ---------------- final kernels (atomic-free) ----------------
__global__ __launch_bounds__(256) void finalY(const u16* __restrict__ h, const float* __restrict__ out_W,
                                              const float* __restrict__ out_b, const float* __restrict__ labels,
                                              const float* __restrict__ is_train, float* __restrict__ preds,
                                              float* __restrict__ bce_part, float* __restrict__ it_part) {
    __shared__ float wbuf[8];
    int tid = threadIdx.x;
    int wave = tid >> 6, lane = tid & 63;
    int cl = lane & 15, quad = lane >> 4;
    int b = blockIdx.x * 16 + wave * 4 + quad;
    const u16x8* hp = (const u16x8*)(h + (size_t)b * HID + cl * 64);
    const float4* wp = (const float4*)(out_W + cl * 64);
    float s = 0.f;
    #pragma unroll
    for (int i = 0; i < 8; ++i) {
        u16x8 hv = hp[i];
        float4 wa = wp[2 * i], wb = wp[2 * i + 1];
        s += b2f(hv[0]) * wa.x + b2f(hv[1]) * wa.y + b2f(hv[2]) * wa.z + b2f(hv[3]) * wa.w
           + b2f(hv[4]) * wb.x + b2f(hv[5]) * wb.y + b2f(hv[6]) * wb.z + b2f(hv[7]) * wb.w;
    }
    s += __shfl_down(s, 8, 16);
    s += __shfl_down(s, 4, 16);
    s += __shfl_down(s, 2, 16);
    s += __shfl_down(s, 1, 16);
    float v1 = 0.f, v2 = 0.f;
    if (cl == 0) {
        float y = s + out_b[0];
        preds[b] = 1.f / (1.f + expf(-y));
        float lab = labels[b], it = is_train[b];
        float mv = fmaxf(-y, 0.f);
        float bce = y - y * lab + mv + logf(expf(-mv) + expf(-y - mv));
        v1 = bce * it; v2 = it;
    }
    v1 += __shfl_xor(v1, 16); v2 += __shfl_xor(v2, 16);
    v1 += __shfl_xor(v1, 32); v2 += __shfl_xor(v2, 32);
    if (lane == 0) { wbuf[wave] = v1; wbuf[4 + wave] = v2; }
    __syncthreads();
    if (tid == 0) {
        bce_part[blockIdx.x] = wbuf[0] + wbuf[1] + wbuf[2] + wbuf[3];
        it_part[blockIdx.x]  = wbuf[4] + wbuf[5] + wbuf[6] + wbuf[7];
    }
}

__global__ __launch_bounds__(256) void finalZ(const float* __restrict__ xnum, const float* __restrict__ xden,
                                              const float* __restrict__ bce_part, const float* __restrict__ it_part,
                                              float* __restrict__ out0) {
    __shared__ float wbuf[12];
    int tid = threadIdx.x, wave = tid >> 6, lane = tid & 63;
    float bs = bce_part[tid], is = it_part[tid];
    #pragma unroll
    for (int off = 32; off; off >>= 1) { bs += __shfl_down(bs, off); is += __shfl_down(is, off); }
    float xl = 0.f;
    for (int t = wave; t < TLEN; t += 4) {
        float n = 0.f, d = 0.f;
        #pragma unroll
        for (int i = 0; i < 4; ++i) { n += xnum[t * 256 + lane + i * 64]; d += xden[t * 256 + lane + i * 64]; }
        #pragma unroll
        for (int off = 32; off; off >>= 1) { n += __shfl_down(n, off); d += __shfl_down(d, off); }
        if (lane == 0) xl += n / (d + 1e-5f);
    }
    if (lane == 0) { wbuf[wave] = xl; wbuf[4 + wave] = bs; wbuf[8 + wave] = is; }
    __syncthreads();
    if (tid == 0) {
        float XL = wbuf[0] + wbuf[1] + wbuf[2] + wbuf[3];
        float BS = wbuf[4] + wbuf[5] + wbuf[6] + wbuf[7];
        float IS = wbuf[8] + wbuf[9] + wbuf[10] + wbuf[11];
        out0[0] = 0.3f * XL + BS / (IS + 1e-5f);
    }
}

// ---------------- launch ----------------
extern "C" void kernel_launch(void* const* d_in, const int* in_sizes, int n_in,
                              void* d_out, int out_size, void* d_ws, size_t ws_size,
                              hipStream_t stream) {
    const float* values   = (const float*)d_in[0];
    const float* masks    = (const float*)d_in[1];
    const float* deltas   = (const float*)d_in[2];
    const float* labels   = (const float*)d_in[3];
    const float* is_train = (const float*)d_in[4];
    const float* td_W     = (const float*)d_in[5];
    const float* td_b     = (const float*)d_in[6];
    const float* W_ih     = (const float*)d_in[7];
    const float* W_hh     = (const float*)d_in[8];
    const float* b_ih     = (const float*)d_in[9];
    const float* b_hh     = (const float*)d_in[10];
    const float* reg_W    = (const float*)d_in[11];
    const float* reg_b    = (const float*)d_in[12];
    const float* out_W    = (const float*)d_in[13];
    const float* out_b    = (const float*)d_in[14];

    float* out = (float*)d_out;

    // workspace: c bf16[BH] | h bf16[BH] | dbuf bf16[48*4096*64] | Xa u8[B*KTOT] | Xb u8[B*KTOT]
    //            | W8 u8[H4*KTOT] | bias f32[H4] | tdWtb bf16[64K] | regW8 u8[48*1024] | parts
    u16*   c      = (u16*)d_ws;
    u16*   h      = c + BH;
    u16*   dbuf   = h + BH;
    u8*    Xa     = (u8*)(dbuf + (size_t)TLEN * BDIM * 64);
    u8*    Xb     = Xa + (size_t)BDIM * KTOT;
    u8*    W8     = Xb + (size_t)BDIM * KTOT;
    float* bias_r = (float*)(W8 + (size_t)H4 * KTOT);
    u16*   tdWtb  = (u16*)(bias_r + H4);
    u8*    regW8  = (u8*)(tdWtb + 1024 * 64);
    float* xnum_part = (float*)(regW8 + 48 * 1024);
    float* xden_part = xnum_part + TLEN * 256;
    float* bce_part  = xden_part + TLEN * 256;
    float* it_part   = bce_part + 256;

    hipMemsetAsync(c, 0, BH * sizeof(u16), stream);                 // c = 0
    hipMemsetAsync(Xa, 0, (size_t)BDIM * KTOT, stream);             // X_hdec(0) = 0 + pad zeros
    hipMemsetAsync(Xb, 0, (size_t)BDIM * KTOT, stream);             // pad zeros (stay zero forever)

    prep_w<<<H4, 256, 0, stream>>>(W_hh, W_ih, W8);
    prep_bias<<<H4 / 256, 256, 0, stream>>>(b_ih, b_hh, bias_r);
    prep_tdwtb<<<256, 256, 0, stream>>>(td_W, tdWtb);
    prep_regw8<<<48, 256, 0, stream>>>(reg_W, regW8);
    prep_dbuf<<<TLEN * 128, 256, 0, stream>>>(deltas, dbuf);

    float* imput = out + 1 + BDIM;
    for (int t = 0; t < TLEN; t++) {
        u8* cur = (t & 1) ? Xb : Xa;
        u8* nxt = (t & 1) ? Xa : Xb;
        const u16* dT1 = dbuf + (size_t)((t + 1 < TLEN) ? (t + 1) : 0) * BDIM * 64;
        stepR<<<BDIM / 16, 256, 0, stream>>>(values, masks, regW8, reg_b, cur, imput,
                                             xnum_part, xden_part, t);
        stepB<<<2048, 256, 0, stream>>>(cur, W8, bias_r, tdWtb, td_b, dT1, c, nxt, h, t == TLEN - 1);
    }
    finalY<<<BDIM / 16, 256, 0, stream>>>(h, out_W, out_b, labels, is_train, out + 1, bce_part, it_part);
    finalZ<<<1, 256, 0, stream>>>(xnum_part, xden_part, bce_part, it_part, out);
}

// Round 10
// 2107.159 us; speedup vs baseline: 7.5995x; 3.1704x over previous
//
#include <hip/hip_runtime.h>
#include <math.h>

// Problem constants
#define BDIM 4096
#define TLEN 48
#define FEAT 35
#define HID 1024
#define H4 4096
#define KTOT 1152      // 1024 (hh) + 128 (ih, 70 real + 58 zero pad)

#define BH ((size_t)BDIM * HID)

typedef unsigned short u16;
typedef unsigned char u8;
typedef __bf16 bf16x8 __attribute__((ext_vector_type(8)));
typedef float f32x4 __attribute__((ext_vector_type(4)));
typedef u16 u16x8 __attribute__((ext_vector_type(8)));
typedef int v8i __attribute__((ext_vector_type(8)));
typedef int v4i __attribute__((ext_vector_type(4)));

#define SCALE1 0x7F7F7F7F   // E8M0 scale = 1.0 in every byte

__device__ __forceinline__ float b2f(u16 u) {
    union { float f; unsigned i; } v; v.i = ((unsigned)u) << 16; return v.f;
}
__device__ __forceinline__ u16 f2b(float f) {
    union { float f; unsigned i; } v; v.f = f;
    unsigned r = v.i + 0x7FFF + ((v.i >> 16) & 1);
    return (u16)(r >> 16);
}
__device__ __forceinline__ unsigned pk4_fp8(float a, float b, float c, float d) {
    int lo = __builtin_amdgcn_cvt_pk_fp8_f32(a, b, 0, false);
    int hi = __builtin_amdgcn_cvt_pk_fp8_f32(c, d, lo, true);
    return (unsigned)hi;
}
__device__ __forceinline__ u8 f2e4m3(float f) {
    return (u8)(__builtin_amdgcn_cvt_pk_fp8_f32(f, 0.f, 0, false) & 0xFF);
}
__device__ __forceinline__ float sigf(float x) { return __builtin_amdgcn_rcpf(1.f + __expf(-x)); }
__device__ __forceinline__ float tanh_fast(float x) { return 1.f - 2.f * __builtin_amdgcn_rcpf(1.f + __expf(2.f * x)); }

// ---------------- prep kernels ----------------
// Combined fp8 weight matrix W[4096][1152], rows reordered (128-wide gate groups, R6):
// orig n = g*HID + j  ->  new n = (j>>5)*128 + g*32 + (j&31)
__global__ __launch_bounds__(256) void prep_w(const float* __restrict__ W_hh, const float* __restrict__ W_ih,
                                              u8* __restrict__ W) {
    int newn = blockIdx.x;
    int nbk = newn >> 7, rem = newn & 127, g = rem >> 5, jl = rem & 31;
    int orig = g * HID + nbk * 32 + jl;
    u8* dst = W + (size_t)newn * KTOT;
    const float* src = W_hh + (size_t)orig * HID;
    const float* src2 = W_ih + (size_t)orig * (2 * FEAT);
    for (int k4 = threadIdx.x; k4 < KTOT / 4; k4 += 256) {
        int k = k4 * 4;
        float f0, f1, f2, f3;
        if (k < HID) {
            f0 = src[k]; f1 = src[k + 1]; f2 = src[k + 2]; f3 = src[k + 3];
        } else {
            int q = k - HID;
            f0 = (q     < 2 * FEAT) ? src2[q]     : 0.f;
            f1 = (q + 1 < 2 * FEAT) ? src2[q + 1] : 0.f;
            f2 = (q + 2 < 2 * FEAT) ? src2[q + 2] : 0.f;
            f3 = (q + 3 < 2 * FEAT) ? src2[q + 3] : 0.f;
        }
        *(unsigned*)(dst + k) = pk4_fp8(f0, f1, f2, f3);
    }
}

__global__ __launch_bounds__(256) void prep_bias(const float* __restrict__ b_ih, const float* __restrict__ b_hh,
                                                 float* __restrict__ bias_r) {
    int newn = blockIdx.x * 256 + threadIdx.x;
    int nbk = newn >> 7, rem = newn & 127, g = rem >> 5, jl = rem & 31;
    int orig = g * HID + nbk * 32 + jl;
    bias_r[newn] = b_ih[orig] + b_hh[orig];
}

// tdWtb[j][f] bf16, [1024][64], f>=35 zero.
__global__ __launch_bounds__(256) void prep_tdwtb(const float* __restrict__ td_W, u16* __restrict__ tdWtb) {
    int idx = blockIdx.x * 256 + threadIdx.x;
    int row = idx >> 6, f = idx & 63;
    tdWtb[idx] = (f < FEAT) ? f2b(td_W[(size_t)row * FEAT + f]) : (u16)0;
}

// regW8[f][k] fp8, [48][1024], f>=35 zero.
__global__ __launch_bounds__(256) void prep_regw8(const float* __restrict__ reg_W, u8* __restrict__ regW8) {
    int row = blockIdx.x;           // 48
    int k = threadIdx.x * 4;        // 1024
    float f0 = 0.f, f1 = 0.f, f2 = 0.f, f3 = 0.f;
    if (row < FEAT) {
        const float* s = reg_W + (size_t)row * HID + k;
        f0 = s[0]; f1 = s[1]; f2 = s[2]; f3 = s[3];
    }
    *(unsigned*)(regW8 + (size_t)row * 1024 + k) = pk4_fp8(f0, f1, f2, f3);
}

// dbuf[t][b][64] bf16 (f>=35 zero), linear layout. Row = 128B.
__global__ __launch_bounds__(256) void prep_dbuf(const float* __restrict__ deltas, u16* __restrict__ dbuf) {
    int bid = blockIdx.x;                 // 48 * 128
    int t = bid >> 7, rc = bid & 127;
    int row = rc * 32 + (threadIdx.x >> 3), cch = threadIdx.x & 7;
    const float* dr = deltas + ((size_t)row * TLEN + t) * FEAT;
    u16x8 tv;
    #pragma unroll
    for (int k = 0; k < 8; ++k) {
        int f = cch * 8 + k;
        tv[k] = (f < FEAT) ? f2b(dr[f]) : (u16)0;
    }
    *(u16x8*)(dbuf + ((size_t)t * BDIM + row) * 64 + cch * 8) = tv;
}

// ---------------- stepR: regression + x_c + loss ----------------
// R9: 512 blocks x 8 rows (2 blocks/CU, was 256 x 16 at 1/CU) to halve the
// latency-bound serial path. A-fragment uses cl&7 row duplication (rows 8-15
// mirror 0-7; duplicates discarded, no OOB). XCD-aligned to stepB's writer map:
// rows [1024p, 1024p+1024) were written on xcd pair {2p, 2p+1}.
__global__ __launch_bounds__(256) void stepR(const float* __restrict__ values, const float* __restrict__ masks,
                                             const u8* __restrict__ regW8, const float* __restrict__ reg_b,
                                             u8* __restrict__ X, float* __restrict__ imput,
                                             float* __restrict__ xnum_part, float* __restrict__ xden_part,
                                             int t) {
    __shared__ float x_sh[8 * 35], m_sh[8 * 35];
    __shared__ float xhp[4][8][49];        // per-wave regression partials (padded)
    __shared__ float redbuf[8];

    int tid = threadIdx.x;
    int wave = tid >> 6, lane = tid & 63;
    int cl = lane & 15, quad = lane >> 4;
    int bid = blockIdx.x;
    int xs = bid & 7, qs = bid >> 3;       // xs: target XCD, qs in [0,64)
    int b0 = (xs >> 1) * 1024 + (xs & 1) * 512 + qs * 8;

    for (int i = tid; i < 8 * 35; i += 256) {
        int b = i / 35, f = i - b * 35;
        size_t g = ((size_t)(b0 + b) * TLEN + t) * FEAT + f;
        x_sh[i] = values[g];
        m_sh[i] = masks[g];
    }
    __syncthreads();

    // ---- regression via MX-fp8 MFMA (K split: wave covers K [wave*256, +256)) ----
    f32x4 racc[3];
    #pragma unroll
    for (int nt = 0; nt < 3; ++nt) racc[nt] = (f32x4){0.f, 0.f, 0.f, 0.f};
    const u8* xrow = X + (size_t)(b0 + (cl & 7)) * KTOT + wave * 256;
    #pragma unroll
    for (int it = 0; it < 2; ++it) {
        v8i av = *(const v8i*)(xrow + it * 128 + quad * 32);
        #pragma unroll
        for (int nt = 0; nt < 3; ++nt) {
            v8i bvv = *(const v8i*)(regW8 + (size_t)(nt * 16 + cl) * 1024 + wave * 256 + it * 128 + quad * 32);
            racc[nt] = __builtin_amdgcn_mfma_scale_f32_16x16x128_f8f6f4(
                av, bvv, racc[nt], 0, 0, 0, SCALE1, 0, SCALE1);
        }
    }
    if (quad < 2) {
        #pragma unroll
        for (int nt = 0; nt < 3; ++nt)
            #pragma unroll
            for (int r = 0; r < 4; ++r)
                xhp[wave][quad * 4 + r][nt * 16 + cl] = racc[nt][r];
    }
    __syncthreads();

    // ---- epilogue: x_c, imputations, X tail (fp8), loss partials ----
    float lossN = 0.f, lossD = 0.f;
    for (int i = tid; i < 8 * 35; i += 256) {
        int b = i / 35, f = i - b * 35;
        float xh = xhp[0][b][f] + xhp[1][b][f] + xhp[2][b][f] + xhp[3][b][f] + reg_b[f];
        float xv = x_sh[i], mv = m_sh[i];
        float xc = mv * xv + (1.f - mv) * xh;
        imput[((size_t)(b0 + b) * TLEN + t) * FEAT + f] = xc;
        u8* Xr = X + (size_t)(b0 + b) * KTOT;
        Xr[HID + f] = f2e4m3(xc);
        Xr[HID + FEAT + f] = f2e4m3(mv);
        lossN += fabsf(xv - xh) * mv;
        lossD += mv;
    }
    #pragma unroll
    for (int off = 32; off; off >>= 1) {
        lossN += __shfl_down(lossN, off);
        lossD += __shfl_down(lossD, off);
    }
    if (lane == 0) { redbuf[wave] = lossN; redbuf[4 + wave] = lossD; }
    __syncthreads();
    if (tid == 0) {
        xnum_part[t * 512 + blockIdx.x] = redbuf[0] + redbuf[1] + redbuf[2] + redbuf[3];
        xden_part[t * 512 + blockIdx.x] = redbuf[4] + redbuf[5] + redbuf[6] + redbuf[7];
    }
}

// ---------------- stepB: MX-fp8 MFMA gates GEMM + fused LSTM cell + inline gamma(t+1) ----------------
// EXACT R6 version (proven: VGPR 112 arch + AGPR acc, no spill, ~36us, FETCH 22MB).
// R7/R8 lesson (final): tile-size changes themselves flip the allocator into spill
// mode regardless of launch bounds -- the 256x128 / 4-wave / acc[4][8] body is the
// only shape that gets the clean AGPR split. Do not touch.
__global__ __launch_bounds__(256, 2) void stepB(const u8* __restrict__ X, const u8* __restrict__ W,
                                                const float* __restrict__ bias_r, const u16* __restrict__ tdWtb,
                                                const float* __restrict__ td_b, const u16* __restrict__ dbufT1,
                                                u16* __restrict__ c, u8* __restrict__ Xn,
                                                u16* __restrict__ h, int last) {
    __shared__ u8 As[256 * 128];
    __shared__ u8 Bs[128 * 128];
    int bid = blockIdx.x;
    int xcd = bid & 7, r0 = bid >> 3;            // r0 in [0,64)
    int mb = (xcd >> 1) * 4 + (r0 & 3);          // [0,16)
    int nb = (xcd & 1) * 16 + (r0 >> 2);         // [0,32)
    int tid = threadIdx.x;
    int wave = tid >> 6, lane = tid & 63;
    int lrow = lane >> 3;            // 0..7 row within 8-row staging group
    int gchunk = (lane & 7) ^ lrow;  // swizzled global 16B-chunk to fetch
    int cl = lane & 15, quad = lane >> 4;
    int c7 = cl & 15 & 7;

    f32x4 acc[4][8];
    #pragma unroll
    for (int mi = 0; mi < 4; ++mi)
        #pragma unroll
        for (int ni = 0; ni < 8; ++ni) acc[mi][ni] = (f32x4){0.f, 0.f, 0.f, 0.f};

    for (int kt = 0; kt < KTOT / 128; ++kt) {     // 9 iterations
        __syncthreads();
        #pragma unroll
        for (int it = 0; it < 8; ++it) {
            int rl = wave * 64 + it * 8;          // A rows [wave*64 .. +64)
            const u8* ga = X + (size_t)(mb * 256 + rl + lrow) * KTOT + kt * 128 + gchunk * 16;
            __builtin_amdgcn_global_load_lds((const __attribute__((address_space(1))) void*)ga,
                                             (__attribute__((address_space(3))) void*)(As + rl * 128),
                                             16, 0, 0);
        }
        #pragma unroll
        for (int it = 0; it < 4; ++it) {
            int rl = wave * 32 + it * 8;          // B rows [wave*32 .. +32)
            const u8* gb = W + (size_t)(nb * 128 + rl + lrow) * KTOT + kt * 128 + gchunk * 16;
            __builtin_amdgcn_global_load_lds((const __attribute__((address_space(1))) void*)gb,
                                             (__attribute__((address_space(3))) void*)(Bs + rl * 128),
                                             16, 0, 0);
        }
        __syncthreads();

        v8i av[4];
        #pragma unroll
        for (int mi = 0; mi < 4; ++mi) {
            const u8* base = As + (wave * 64 + mi * 16 + cl) * 128;
            v4i lo = *(const v4i*)(base + (((2 * quad) ^ c7) << 4));
            v4i hi = *(const v4i*)(base + (((2 * quad + 1) ^ c7) << 4));
            av[mi] = (v8i){lo[0], lo[1], lo[2], lo[3], hi[0], hi[1], hi[2], hi[3]};
        }
        #pragma unroll
        for (int ni = 0; ni < 8; ++ni) {
            const u8* base = Bs + (ni * 16 + cl) * 128;
            v4i lo = *(const v4i*)(base + (((2 * quad) ^ c7) << 4));
            v4i hi = *(const v4i*)(base + (((2 * quad + 1) ^ c7) << 4));
            v8i bvv = (v8i){lo[0], lo[1], lo[2], lo[3], hi[0], hi[1], hi[2], hi[3]};
            #pragma unroll
            for (int mi = 0; mi < 4; ++mi)
                acc[mi][ni] = __builtin_amdgcn_mfma_scale_f32_16x16x128_f8f6f4(
                    av[mi], bvv, acc[mi][ni], 0, 0, 0, SCALE1, 0, SCALE1);
        }
    }

    // ---- restage As with deltas(t+1) bf16 [256 rows][64] for inline gamma ----
    if (!last) {
        __syncthreads();   // all waves done with K-loop LDS
        const u8* gd = (const u8*)dbufT1 + (size_t)(mb * 256) * 128;
        #pragma unroll
        for (int it = 0; it < 8; ++it) {
            int rl = wave * 64 + it * 8;
            __builtin_amdgcn_global_load_lds((const __attribute__((address_space(1))) void*)(gd + (size_t)(rl + lrow) * 128 + gchunk * 16),
                                             (__attribute__((address_space(3))) void*)(As + rl * 128),
                                             16, 0, 0);
        }
        __syncthreads();
    }

    // ---- fused epilogue: gamma(t+1) MFMA per mi-tile + LSTM cell ----
    const u16* Asw = (const u16*)As;
    int swc0 = quad ^ c7, swc1 = (4 + quad) ^ c7;
    #pragma unroll
    for (int mi = 0; mi < 4; ++mi) {
        float gam[2][4] = {{1.f, 1.f, 1.f, 1.f}, {1.f, 1.f, 1.f, 1.f}};
        if (!last) {
            int arow = wave * 64 + mi * 16 + cl;
            bf16x8 a0 = *(const bf16x8*)(Asw + arow * 64 + swc0 * 8);
            bf16x8 a1 = *(const bf16x8*)(Asw + arow * 64 + swc1 * 8);
            #pragma unroll
            for (int jh = 0; jh < 2; ++jh) {
                const u16* tw = tdWtb + (size_t)(nb * 32 + jh * 16 + cl) * 64;
                bf16x8 b0v = *(const bf16x8*)(tw + quad * 8);
                bf16x8 b1v = *(const bf16x8*)(tw + 32 + quad * 8);
                f32x4 g4 = (f32x4){0.f, 0.f, 0.f, 0.f};
                g4 = __builtin_amdgcn_mfma_f32_16x16x32_bf16(a0, b0v, g4, 0, 0, 0);
                g4 = __builtin_amdgcn_mfma_f32_16x16x32_bf16(a1, b1v, g4, 0, 0, 0);
                float4 tb = *(const float4*)(td_b + nb * 32 + jh * 16 + quad * 4);
                float tbv[4] = {tb.x, tb.y, tb.z, tb.w};
                #pragma unroll
                for (int r = 0; r < 4; ++r)
                    gam[jh][r] = __expf(-fmaxf(g4[r] + tbv[r], 0.f));
            }
        }
        #pragma unroll
        for (int r = 0; r < 4; ++r) {
            int b = mb * 256 + wave * 64 + mi * 16 + quad * 4 + r;
            #pragma unroll
            for (int jh = 0; jh < 2; ++jh) {
                int jl = jh * 16 + cl;
                int j = nb * 32 + jl;
                float iv = acc[mi][jh + 0][r] + bias_r[nb * 128 + jl];
                float fv = acc[mi][jh + 2][r] + bias_r[nb * 128 + 32 + jl];
                float gg = acc[mi][jh + 4][r] + bias_r[nb * 128 + 64 + jl];
                float ov = acc[mi][jh + 6][r] + bias_r[nb * 128 + 96 + jl];
                iv = sigf(iv); fv = sigf(fv); ov = sigf(ov); gg = tanh_fast(gg);
                size_t idx = (size_t)b * HID + j;
                float cn = fv * b2f(c[idx]) + iv * gg;
                c[idx] = f2b(cn);
                float hn = ov * tanh_fast(cn);
                if (last) {
                    h[idx] = f2b(hn);
                } else {
                    Xn[(size_t)b * KTOT + j] = f2e4m3(hn * gam[jh][r]);
                }
            }
        }
    }
}

// ---------------- final kernels (atomic-free) ----------------
__global__ __launch_bounds__(256) void finalY(const u16* __restrict__ h, const float* __restrict__ out_W,
                                              const float* __restrict__ out_b, const float* __restrict__ labels,
                                              const float* __restrict__ is_train, float* __restrict__ preds,
                                              float* __restrict__ bce_part, float* __restrict__ it_part) {
    __shared__ float wbuf[8];
    int tid = threadIdx.x;
    int wave = tid >> 6, lane = tid & 63;
    int cl = lane & 15, quad = lane >> 4;
    int b = blockIdx.x * 16 + wave * 4 + quad;
    const u16x8* hp = (const u16x8*)(h + (size_t)b * HID + cl * 64);
    const float4* wp = (const float4*)(out_W + cl * 64);
    float s = 0.f;
    #pragma unroll
    for (int i = 0; i < 8; ++i) {
        u16x8 hv = hp[i];
        float4 wa = wp[2 * i], wb = wp[2 * i + 1];
        s += b2f(hv[0]) * wa.x + b2f(hv[1]) * wa.y + b2f(hv[2]) * wa.z + b2f(hv[3]) * wa.w
           + b2f(hv[4]) * wb.x + b2f(hv[5]) * wb.y + b2f(hv[6]) * wb.z + b2f(hv[7]) * wb.w;
    }
    s += __shfl_down(s, 8, 16);
    s += __shfl_down(s, 4, 16);
    s += __shfl_down(s, 2, 16);
    s += __shfl_down(s, 1, 16);
    float v1 = 0.f, v2 = 0.f;
    if (cl == 0) {
        float y = s + out_b[0];
        preds[b] = 1.f / (1.f + expf(-y));
        float lab = labels[b], it = is_train[b];
        float mv = fmaxf(-y, 0.f);
        float bce = y - y * lab + mv + logf(expf(-mv) + expf(-y - mv));
        v1 = bce * it; v2 = it;
    }
    v1 += __shfl_xor(v1, 16); v2 += __shfl_xor(v2, 16);
    v1 += __shfl_xor(v1, 32); v2 += __shfl_xor(v2, 32);
    if (lane == 0) { wbuf[wave] = v1; wbuf[4 + wave] = v2; }
    __syncthreads();
    if (tid == 0) {
        bce_part[blockIdx.x] = wbuf[0] + wbuf[1] + wbuf[2] + wbuf[3];
        it_part[blockIdx.x]  = wbuf[4] + wbuf[5] + wbuf[6] + wbuf[7];
    }
}

__global__ __launch_bounds__(256) void finalZ(const float* __restrict__ xnum, const float* __restrict__ xden,
                                              const float* __restrict__ bce_part, const float* __restrict__ it_part,
                                              float* __restrict__ out0) {
    __shared__ float wbuf[12];
    int tid = threadIdx.x, wave = tid >> 6, lane = tid & 63;
    float bs = bce_part[tid], is = it_part[tid];
    #pragma unroll
    for (int off = 32; off; off >>= 1) { bs += __shfl_down(bs, off); is += __shfl_down(is, off); }
    float xl = 0.f;
    for (int t = wave; t < TLEN; t += 4) {
        float n = 0.f, d = 0.f;
        #pragma unroll
        for (int i = 0; i < 8; ++i) { n += xnum[t * 512 + lane + i * 64]; d += xden[t * 512 + lane + i * 64]; }
        #pragma unroll
        for (int off = 32; off; off >>= 1) { n += __shfl_down(n, off); d += __shfl_down(d, off); }
        if (lane == 0) xl += n / (d + 1e-5f);
    }
    if (lane == 0) { wbuf[wave] = xl; wbuf[4 + wave] = bs; wbuf[8 + wave] = is; }
    __syncthreads();
    if (tid == 0) {
        float XL = wbuf[0] + wbuf[1] + wbuf[2] + wbuf[3];
        float BS = wbuf[4] + wbuf[5] + wbuf[6] + wbuf[7];
        float IS = wbuf[8] + wbuf[9] + wbuf[10] + wbuf[11];
        out0[0] = 0.3f * XL + BS / (IS + 1e-5f);
    }
}

// ---------------- launch ----------------
extern "C" void kernel_launch(void* const* d_in, const int* in_sizes, int n_in,
                              void* d_out, int out_size, void* d_ws, size_t ws_size,
                              hipStream_t stream) {
    const float* values   = (const float*)d_in[0];
    const float* masks    = (const float*)d_in[1];
    const float* deltas   = (const float*)d_in[2];
    const float* labels   = (const float*)d_in[3];
    const float* is_train = (const float*)d_in[4];
    const float* td_W     = (const float*)d_in[5];
    const float* td_b     = (const float*)d_in[6];
    const float* W_ih     = (const float*)d_in[7];
    const float* W_hh     = (const float*)d_in[8];
    const float* b_ih     = (const float*)d_in[9];
    const float* b_hh     = (const float*)d_in[10];
    const float* reg_W    = (const float*)d_in[11];
    const float* reg_b    = (const float*)d_in[12];
    const float* out_W    = (const float*)d_in[13];
    const float* out_b    = (const float*)d_in[14];

    float* out = (float*)d_out;

    // workspace: c bf16[BH] | h bf16[BH] | dbuf bf16[48*4096*64] | Xa u8[B*KTOT] | Xb u8[B*KTOT]
    //            | W8 u8[H4*KTOT] | bias f32[H4] | tdWtb bf16[64K] | regW8 u8[48*1024] | parts
    u16*   c      = (u16*)d_ws;
    u16*   h      = c + BH;
    u16*   dbuf   = h + BH;
    u8*    Xa     = (u8*)(dbuf + (size_t)TLEN * BDIM * 64);
    u8*    Xb     = Xa + (size_t)BDIM * KTOT;
    u8*    W8     = Xb + (size_t)BDIM * KTOT;
    float* bias_r = (float*)(W8 + (size_t)H4 * KTOT);
    u16*   tdWtb  = (u16*)(bias_r + H4);
    u8*    regW8  = (u8*)(tdWtb + 1024 * 64);
    float* xnum_part = (float*)(regW8 + 48 * 1024);
    float* xden_part = xnum_part + TLEN * 512;
    float* bce_part  = xden_part + TLEN * 512;
    float* it_part   = bce_part + 256;

    hipMemsetAsync(c, 0, BH * sizeof(u16), stream);                 // c = 0
    hipMemsetAsync(Xa, 0, (size_t)BDIM * KTOT, stream);             // X_hdec(0) = 0 + pad zeros
    hipMemsetAsync(Xb, 0, (size_t)BDIM * KTOT, stream);             // pad zeros (stay zero forever)

    prep_w<<<H4, 256, 0, stream>>>(W_hh, W_ih, W8);
    prep_bias<<<H4 / 256, 256, 0, stream>>>(b_ih, b_hh, bias_r);
    prep_tdwtb<<<256, 256, 0, stream>>>(td_W, tdWtb);
    prep_regw8<<<48, 256, 0, stream>>>(reg_W, regW8);
    prep_dbuf<<<TLEN * 128, 256, 0, stream>>>(deltas, dbuf);

    float* imput = out + 1 + BDIM;
    for (int t = 0; t < TLEN; t++) {
        u8* cur = (t & 1) ? Xb : Xa;
        u8* nxt = (t & 1) ? Xa : Xb;
        const u16* dT1 = dbuf + (size_t)((t + 1 < TLEN) ? (t + 1) : 0) * BDIM * 64;
        stepR<<<512, 256, 0, stream>>>(values, masks, regW8, reg_b, cur, imput,
                                       xnum_part, xden_part, t);
        stepB<<<512, 256, 0, stream>>>(cur, W8, bias_r, tdWtb, td_b, dT1, c, nxt, h, t == TLEN - 1);
    }
    finalY<<<BDIM / 16, 256, 0, stream>>>(h, out_W, out_b, labels, is_train, out + 1, bce_part, it_part);
    finalZ<<<1, 256, 0, stream>>>(xnum_part, xden_part, bce_part, it_part, out);
}